// Round 7
// baseline (251.799 us; speedup 1.0000x reference)
//
#include <hip/hip_runtime.h>

typedef _Float16 v8h __attribute__((ext_vector_type(8)));
typedef _Float16 v4h __attribute__((ext_vector_type(4)));
typedef float f32x4 __attribute__((ext_vector_type(4)));

#define TT 4096
#define NB 4
#define NROW (NB * TT)
#define LOG2E 1.44269504088896f

#define MFMA16(A, B, C) __builtin_amdgcn_mfma_f32_16x16x32_f16((A), (B), (C), 0, 0, 0)

// ---------- prep: W (fp32 [1024][64] x3) -> WT f16 [192][1024] ----------
// row = mat*64 + h; mat 0=Q (pre-scaled by 0.125*log2e), 1=K, 2=V.
__global__ __launch_bounds__(256) void prep_w(
    const float* __restrict__ Wk, const float* __restrict__ Wq, const float* __restrict__ Wv,
    _Float16* __restrict__ WT) {
  const int row = blockIdx.x;          // 0..191
  const int mI = row >> 6, h = row & 63;
  const float* src = (mI == 0) ? Wq : ((mI == 1) ? Wk : Wv);
  const float scale = (mI == 0) ? 0.125f * LOG2E : 1.0f;
  for (int c = threadIdx.x; c < 1024; c += 256)
    WT[row * 1024 + c] = (_Float16)(src[c * 64 + h] * scale);
}

// ---------- projection via f16 MFMA ----------
// 768 blocks x 256 thr; wave tile = 16 rows x 64 cols (one matrix); K-step 64.
__global__ __launch_bounds__(256, 4) void proj_kernel(
    const float* __restrict__ x, const _Float16* __restrict__ WT,
    _Float16* __restrict__ Qf, _Float16* __restrict__ Kf, _Float16* __restrict__ VTf) {
  const int t = threadIdx.x;
  const int lane = t & 63;
  const int wv = t >> 6;
  const int g = lane >> 4;
  const int q15 = lane & 15;
  const int bid = blockIdx.x;
  const int mat = bid >> 8;                    // 0=Q, 1=K, 2=V
  const int rb = (bid & 255) * 64 + wv * 16;
  const int rowA = rb + q15;

  const _Float16* WB = WT + mat * 64 * 1024;

  f32x4 acc[4] = {};

  for (int c0 = 0; c0 < 1024; c0 += 64) {
    const long xb0 = (long)rowA * 1024 + c0 + g * 8;
    f32x4 fa0 = *(const f32x4*)&x[xb0];
    f32x4 fa1 = *(const f32x4*)&x[xb0 + 4];
    f32x4 fb0 = *(const f32x4*)&x[xb0 + 32];
    f32x4 fb1 = *(const f32x4*)&x[xb0 + 36];
    v8h xa, xb;
#pragma unroll
    for (int i = 0; i < 4; ++i) {
      xa[i] = (_Float16)fa0[i];
      xa[4 + i] = (_Float16)fa1[i];
      xb[i] = (_Float16)fb0[i];
      xb[4 + i] = (_Float16)fb1[i];
    }
    v8h wa[4], wb[4];
#pragma unroll
    for (int ct = 0; ct < 4; ++ct) {
      const int wrow = (ct * 16 + q15) * 1024 + c0 + g * 8;
      wa[ct] = *(const v8h*)&WB[wrow];
      wb[ct] = *(const v8h*)&WB[wrow + 32];
    }
#pragma unroll
    for (int ct = 0; ct < 4; ++ct) {
      acc[ct] = MFMA16(xa, wa[ct], acc[ct]);
      acc[ct] = MFMA16(xb, wb[ct], acc[ct]);
    }
  }

#pragma unroll
  for (int ct = 0; ct < 4; ++ct) {
    const int h = ct * 16 + q15;
    if (mat == 2) {
      // V transposed [b][h][t]; 4 consecutive t per lane -> packed 8B store
      const int row0 = rb + g * 4;
      const int b = row0 >> 12, tb = row0 & 4095;
      v4h pv;
#pragma unroll
      for (int r = 0; r < 4; ++r) pv[r] = (_Float16)acc[ct][r];
      *(v4h*)&VTf[((long)(b * 64 + h)) * 4096 + tb] = pv;
    } else {
      _Float16* dst = (mat == 0) ? Qf : Kf;
#pragma unroll
      for (int r = 0; r < 4; ++r) {
        const int row = rb + g * 4 + r;
        dst[row * 64 + h] = (_Float16)acc[ct][r];
      }
    }
  }
}

// ---------- causal flash attention, f16 MFMA, 4-way intra-block split-K ----------
// 1024 blocks x 256 thr (4 waves). Wave w handles chunks c = w, w+4, ... (32 keys)
// with private online-softmax state; LDS combine at the end.
// qt permutation: placement-robust balance. r = bid>>2; v = ((r>>2)<<1)|(r&1),
// u = (r>>1)&1, qt = u ? 255-v : v. Bijective, and every co-resident quadruple
// (bid stride-8 via XCD round-robin, or bid-consecutive) sums to 510 chunks.
__global__ __launch_bounds__(256, 4) void attn_kernel(
    const _Float16* __restrict__ Qf, const _Float16* __restrict__ Kf,
    const _Float16* __restrict__ VTf, float* __restrict__ out) {
  const int t = threadIdx.x;
  const int lane = t & 63;
  const int wv = t >> 6;
  const int g = lane >> 4;
  const int q15 = lane & 15;
  const int bid = blockIdx.x;
  const int b = bid & 3;
  const int r = bid >> 2;
  const int vv = ((r >> 2) << 1) | (r & 1);
  const int qt = ((r >> 1) & 1) ? 255 - vv : vv;   // balanced permutation
  const int qbase = qt * 16;
  const int bbase = b * TT;
  const int qg = qbase + q15;
  const int nfull = qbase >> 5;          // last (diagonal) chunk index

  __shared__ float red_m[4][16];
  __shared__ float red_l[4][16];
  __shared__ float osum[16][65];

  // Q fragments (B-operand): lane holds Q[q15][chunk*32 + g*8 + i]
  const int qrow = (bbase + qbase + q15) * 64;
  const v8h q0 = *(const v8h*)&Qf[qrow + g * 8];
  const v8h q1 = *(const v8h*)&Qf[qrow + 32 + g * 8];

  f32x4 o[4] = {};
  float m = -1e30f, l = 0.f;

  // permuted key row base: key = KB + 8*(rho>>2) + 4*f + (rho&3), rho = q15 (A-row)
  const int kperm = bbase + 8 * (q15 >> 2) + (q15 & 3);
  const int vrow = b * 64;

  v8h KF[2][2], VF[4];

  auto loadK = [&](int KB) {
#pragma unroll
    for (int f = 0; f < 2; ++f)
#pragma unroll
      for (int ch = 0; ch < 2; ++ch)
        KF[f][ch] = *(const v8h*)&Kf[(kperm + KB + 4 * f) * 64 + ch * 32 + g * 8];
  };
  auto loadV = [&](int KB) {
#pragma unroll
    for (int ht = 0; ht < 4; ++ht)
      VF[ht] = *(const v8h*)&VTf[(long)(vrow + ht * 16 + q15) * 4096 + KB + g * 8];
  };

  if (wv <= nfull) {
    int c = wv;
    loadK(c * 32);
    loadV(c * 32);
    for (;;) {
      // ---- QK^T (S^T frags == PV B-operand layout via kperm) ----
      f32x4 s0 = {}, s1 = {};
      __builtin_amdgcn_s_setprio(1);
      s0 = MFMA16(KF[0][0], q0, s0);
      s0 = MFMA16(KF[0][1], q1, s0);
      s1 = MFMA16(KF[1][0], q0, s1);
      s1 = MFMA16(KF[1][1], q1, s1);
      __builtin_amdgcn_s_setprio(0);

      const int nxt = c + 4;
      if (nxt <= nfull) loadK(nxt * 32);   // pipeline: K consumed above

      if (c == nfull) {                    // causal mask (permuted key ids)
        const int kk = c * 32 + 8 * g;
#pragma unroll
        for (int rr = 0; rr < 4; ++rr) {
          if (kk + rr > qg)     s0[rr] = -1e30f;
          if (kk + 4 + rr > qg) s1[rr] = -1e30f;
        }
      }

      float pmax = fmaxf(fmaxf(fmaxf(s0[0], s0[1]), fmaxf(s0[2], s0[3])),
                         fmaxf(fmaxf(s1[0], s1[1]), fmaxf(s1[2], s1[3])));
      pmax = fmaxf(pmax, __shfl_xor(pmax, 16));
      pmax = fmaxf(pmax, __shfl_xor(pmax, 32));
      if (!__all(pmax <= m + 8.0f)) {      // defer-max (log2 domain)
        const float mn = fmaxf(m, pmax);
        const float corr = __builtin_amdgcn_exp2f(m - mn);
        l *= corr;
#pragma unroll
        for (int ht = 0; ht < 4; ++ht)
#pragma unroll
          for (int j = 0; j < 4; ++j) o[ht][j] *= corr;
        m = mn;
      }
      float ls = 0.f;
#pragma unroll
      for (int rr = 0; rr < 4; ++rr) { s0[rr] = __builtin_amdgcn_exp2f(s0[rr] - m); ls += s0[rr]; }
#pragma unroll
      for (int rr = 0; rr < 4; ++rr) { s1[rr] = __builtin_amdgcn_exp2f(s1[rr] - m); ls += s1[rr]; }
      ls += __shfl_xor(ls, 16);
      ls += __shfl_xor(ls, 32);
      l += ls;

      v8h ph;
#pragma unroll
      for (int rr = 0; rr < 4; ++rr) {
        ph[rr] = (_Float16)s0[rr];
        ph[4 + rr] = (_Float16)s1[rr];
      }
      __builtin_amdgcn_s_setprio(1);
#pragma unroll
      for (int ht = 0; ht < 4; ++ht) o[ht] = MFMA16(VF[ht], ph, o[ht]);
      __builtin_amdgcn_s_setprio(0);

      if (nxt > nfull) break;
      loadV(nxt * 32);                     // pipeline: V consumed above
      c = nxt;
    }
  }

  // ---- cross-wave combine ----
  if (lane < 16) { red_m[wv][q15] = m; red_l[wv][q15] = l; }
  for (int i = t; i < 16 * 65; i += 256) ((float*)osum)[i] = 0.f;
  __syncthreads();

  const float gm = fmaxf(fmaxf(red_m[0][q15], red_m[1][q15]),
                         fmaxf(red_m[2][q15], red_m[3][q15]));
  const float myscale = __builtin_amdgcn_exp2f(m - gm);

#pragma unroll
  for (int w = 0; w < 4; ++w) {
    if (wv == w) {
#pragma unroll
      for (int ht = 0; ht < 4; ++ht)
#pragma unroll
        for (int j = 0; j < 4; ++j)
          osum[q15][ht * 16 + g * 4 + j] += o[ht][j] * myscale;
    }
    __syncthreads();
  }

  // ---- store ----
  const int q = t >> 4;
  const int h0 = (t & 15) * 4;
  const float gmq = fmaxf(fmaxf(red_m[0][q], red_m[1][q]),
                          fmaxf(red_m[2][q], red_m[3][q]));
  float lt = 0.f;
#pragma unroll
  for (int w = 0; w < 4; ++w)
    lt += red_l[w][q] * __builtin_amdgcn_exp2f(red_m[w][q] - gmq);
  const float inv = 1.0f / lt;
  f32x4 v;
#pragma unroll
  for (int j = 0; j < 4; ++j) v[j] = osum[q][h0 + j] * inv;
  *(f32x4*)&out[(long)(bbase + qbase + q) * 64 + h0] = v;
}

extern "C" void kernel_launch(void* const* d_in, const int* in_sizes, int n_in,
                              void* d_out, int out_size, void* d_ws, size_t ws_size,
                              hipStream_t stream) {
  const float* x  = (const float*)d_in[0];
  const float* Wk = (const float*)d_in[1];
  const float* Wq = (const float*)d_in[2];
  const float* Wv = (const float*)d_in[3];
  float* out = (float*)d_out;

  // ws: 3 arrays x 1M f16 = 6.3 MB
  _Float16* Qf  = (_Float16*)d_ws;
  _Float16* Kf  = Qf + NROW * 64;
  _Float16* VTf = Kf + NROW * 64;

  // W^T scratch lives in d_out (consumed by proj; attn fully overwrites d_out)
  _Float16* WT = (_Float16*)d_out;

  prep_w<<<192, 256, 0, stream>>>(Wk, Wq, Wv, WT);
  proj_kernel<<<768, 256, 0, stream>>>(x, WT, Qf, Kf, VTf);
  attn_kernel<<<1024, 256, 0, stream>>>(Qf, Kf, VTf, out);
}